// Round 1
// baseline (2402.842 us; speedup 1.0000x reference)
//
#include <hip/hip_runtime.h>

typedef int   v4i  __attribute__((ext_vector_type(4)));
typedef int   v16i __attribute__((ext_vector_type(16)));
typedef float f4   __attribute__((ext_vector_type(4)));

#define DD 4096
#define BATCH 16384

// ---------------- binarize: f32 -> i8 sign plane (4 elems/thread) ----------------
__global__ void binarize_k(const float* __restrict__ w, unsigned int* __restrict__ o, int n4) {
  int i = blockIdx.x * blockDim.x + threadIdx.x;
  if (i >= n4) return;
  f4 v = ((const f4*)w)[i];
  unsigned int r = 0;
#pragma unroll
  for (int j = 0; j < 4; ++j) {
    unsigned int b = (v[j] >= 0.0f) ? 0x01u : 0xFFu;
    r |= b << (8 * j);
  }
  o[i] = r;
}

// ---------------- row-sum of binarized w0 (one wave per row) ----------------
__global__ void rowsum_k(const signed char* __restrict__ wb, int* __restrict__ R) {
  int lane = threadIdx.x & 63, wid = threadIdx.x >> 6;
  int row = blockIdx.x * 4 + wid;
  const signed char* p = wb + (size_t)row * DD;
  int s = 0;
#pragma unroll
  for (int j = 0; j < 4; ++j) {
    v4i a = *(const v4i*)(p + lane * 16 + j * 1024);
#pragma unroll
    for (int w = 0; w < 4; ++w) {
      unsigned int xa = (unsigned int)a[w];
#pragma unroll
      for (int by = 0; by < 4; ++by)
        s += (int)(signed char)((xa >> (8 * by)) & 255u);
    }
  }
#pragma unroll
  for (int off = 32; off > 0; off >>= 1) s += __shfl_down(s, off);
  if (lane == 0) R[row] = s;
}

// ---------------- layer 0: x(f32) x sign(w0) via 4 exact i8 digit planes ----------------
// X = trunc(x*2^27); Y = X + 2^30 (>=0, <2^31); digit_k = byte_k(Y) - 128 (XOR 0x80).
// z*2^27 = sum_k 2^{8k}*SA_k + R_o*(128*16843009 - 2^30) = ... + 1082163328*R_o  (exact int)
__global__ __launch_bounds__(512, 2) void gemm0_k(
    const float* __restrict__ x, const signed char* __restrict__ wb,
    const int* __restrict__ R, const float* __restrict__ bias,
    signed char* __restrict__ h1) {
  __shared__ signed char As[2][4][128 * 80];  // 4 digit planes, rows padded to 80B
  __shared__ signed char Bs[2][128 * 80];
  const int tid = threadIdx.x;
  const int lane = tid & 63, wid = tid >> 6;
  const int wm = wid >> 1, wn = wid & 1;          // 4x2 wave grid, wave tile 32x64
  const int n0 = blockIdx.x * 128, m0 = blockIdx.y * 128;

  v16i acc[4][2];
#pragma unroll
  for (int d = 0; d < 4; ++d)
#pragma unroll
    for (int f = 0; f < 2; ++f)
#pragma unroll
      for (int e = 0; e < 16; ++e) acc[d][f][e] = 0;

  const int arow_l = tid >> 4;       // 0..31 (x f32 staging)
  const int aseg   = tid & 15;       // 0..15 -> 16B seg
  const int brow   = tid >> 2;       // 0..127 (w0b staging)
  const int bseg   = (tid & 3) * 16;

  f4 va[4]; v4i vb;

  auto loadTile = [&](int kpos) {
#pragma unroll
    for (int p = 0; p < 4; ++p) {
      int row = p * 32 + arow_l;
      va[p] = *(const f4*)(x + (size_t)(m0 + row) * DD + kpos + aseg * 4);
    }
    vb = *(const v4i*)(wb + (size_t)(n0 + brow) * DD + kpos + bseg);
  };
  auto writeTile = [&](int bf) {
#pragma unroll
    for (int p = 0; p < 4; ++p) {
      int row = p * 32 + arow_l;
      unsigned int Y[4];
#pragma unroll
      for (int j = 0; j < 4; ++j) {
        int X = (int)(va[p][j] * 134217728.0f);   // exact for |x|>=2^-4
        Y[j] = (unsigned int)(X + 1073741824);
      }
#pragma unroll
      for (int k = 0; k < 4; ++k) {
        unsigned int wv = ((Y[0] >> (8 * k)) & 255u)
                        | (((Y[1] >> (8 * k)) & 255u) << 8)
                        | (((Y[2] >> (8 * k)) & 255u) << 16)
                        | (((Y[3] >> (8 * k)) & 255u) << 24);
        wv ^= 0x80808080u;  // bias each byte by -128 -> signed digit
        *(unsigned int*)&As[bf][k][row * 80 + aseg * 4] = wv;
      }
    }
    *(v4i*)&Bs[bf][brow * 80 + bseg] = vb;
  };

  loadTile(0);
  writeTile(0);
  __syncthreads();

  for (int t = 0; t < 64; ++t) {
    int cur = t & 1;
    if (t < 63) loadTile((t + 1) * 64);
#pragma unroll
    for (int kt = 0; kt < 2; ++kt) {
      int koff = kt * 32 + (lane >> 5) * 16;
      int ar = (wm * 32 + (lane & 31)) * 80 + koff;
      v4i a[4], b[2];
#pragma unroll
      for (int d = 0; d < 4; ++d) a[d] = *(const v4i*)&As[cur][d][ar];
#pragma unroll
      for (int f = 0; f < 2; ++f)
        b[f] = *(const v4i*)&Bs[cur][(wn * 64 + f * 32 + (lane & 31)) * 80 + koff];
#pragma unroll
      for (int d = 0; d < 4; ++d)
#pragma unroll
        for (int f = 0; f < 2; ++f)
          acc[d][f] = __builtin_amdgcn_mfma_i32_32x32x32_i8(a[d], b[f], acc[d][f], 0, 0, 0);
    }
    if (t < 63) writeTile(cur ^ 1);
    __syncthreads();
  }

#pragma unroll
  for (int f = 0; f < 2; ++f) {
    int col = n0 + wn * 64 + f * 32 + (lane & 31);
    long long rterm = 1082163328LL * (long long)R[col];
    double bb = (double)bias[col];
#pragma unroll
    for (int r = 0; r < 16; ++r) {
      long long Z = (long long)acc[0][f][r] + 256LL * (long long)acc[1][f][r]
                  + 65536LL * (long long)acc[2][f][r] + 16777216LL * (long long)acc[3][f][r]
                  + rterm;
      double z = (double)Z * 7.450580596923828125e-9 + bb;  // * 2^-27
      int row = m0 + wm * 32 + (r & 3) + 8 * (r >> 2) + 4 * (lane >> 5);
      h1[(size_t)row * DD + col] = (z >= 0.0) ? (signed char)1 : (signed char)(-1);
    }
  }
}

// ---------------- binary x binary layers (exact i32) ----------------
__global__ __launch_bounds__(512, 2) void gemm_bin_k(
    const signed char* __restrict__ A, const signed char* __restrict__ Bw,
    const float* __restrict__ bias, signed char* __restrict__ out) {
  __shared__ signed char As[2][256 * 80];
  __shared__ signed char Bs[2][256 * 80];
  const int tid = threadIdx.x, lane = tid & 63, wid = tid >> 6;
  const int wm = wid >> 2, wn = wid & 3;          // 2x4 wave grid, wave tile 128x64
  const int n0 = blockIdx.x * 256, m0 = blockIdx.y * 256;

  v16i acc[4][2];
#pragma unroll
  for (int mi = 0; mi < 4; ++mi)
#pragma unroll
    for (int f = 0; f < 2; ++f)
#pragma unroll
      for (int e = 0; e < 16; ++e) acc[mi][f][e] = 0;

  const int srow = tid >> 1;           // 0..255
  const int sseg = (tid & 1) * 32;     // 0 / 32

  v4i la0, la1, lb0, lb1;
  auto loadTile = [&](int kpos) {
    la0 = *(const v4i*)(A  + (size_t)(m0 + srow) * DD + kpos + sseg);
    la1 = *(const v4i*)(A  + (size_t)(m0 + srow) * DD + kpos + sseg + 16);
    lb0 = *(const v4i*)(Bw + (size_t)(n0 + srow) * DD + kpos + sseg);
    lb1 = *(const v4i*)(Bw + (size_t)(n0 + srow) * DD + kpos + sseg + 16);
  };
  auto writeTile = [&](int bf) {
    *(v4i*)&As[bf][srow * 80 + sseg]      = la0;
    *(v4i*)&As[bf][srow * 80 + sseg + 16] = la1;
    *(v4i*)&Bs[bf][srow * 80 + sseg]      = lb0;
    *(v4i*)&Bs[bf][srow * 80 + sseg + 16] = lb1;
  };

  loadTile(0);
  writeTile(0);
  __syncthreads();

  for (int t = 0; t < 64; ++t) {
    int cur = t & 1;
    if (t < 63) loadTile((t + 1) * 64);
#pragma unroll
    for (int kt = 0; kt < 2; ++kt) {
      int koff = kt * 32 + (lane >> 5) * 16;
      v4i a[4], b[2];
#pragma unroll
      for (int mi = 0; mi < 4; ++mi)
        a[mi] = *(const v4i*)&As[cur][(wm * 128 + mi * 32 + (lane & 31)) * 80 + koff];
#pragma unroll
      for (int f = 0; f < 2; ++f)
        b[f] = *(const v4i*)&Bs[cur][(wn * 64 + f * 32 + (lane & 31)) * 80 + koff];
#pragma unroll
      for (int mi = 0; mi < 4; ++mi)
#pragma unroll
        for (int f = 0; f < 2; ++f)
          acc[mi][f] = __builtin_amdgcn_mfma_i32_32x32x32_i8(a[mi], b[f], acc[mi][f], 0, 0, 0);
    }
    if (t < 63) writeTile(cur ^ 1);
    __syncthreads();
  }

#pragma unroll
  for (int mi = 0; mi < 4; ++mi)
#pragma unroll
    for (int f = 0; f < 2; ++f) {
      int col = n0 + wn * 64 + f * 32 + (lane & 31);
      float bb = bias[col];
#pragma unroll
      for (int r = 0; r < 16; ++r) {
        float z = (float)acc[mi][f][r] + bb;   // exact: |acc|<=4096 integer
        int row = m0 + wm * 128 + mi * 32 + (r & 3) + 8 * (r >> 2) + 4 * (lane >> 5);
        out[(size_t)row * DD + col] = (z >= 0.0f) ? (signed char)1 : (signed char)(-1);
      }
    }
}

// ---------------- final layer: [16384,4096] x [1,4096] -> sign -> f32 ----------------
__global__ void final_k(const signed char* __restrict__ h, const signed char* __restrict__ w3b,
                        const float* __restrict__ b3, float* __restrict__ out) {
  int lane = threadIdx.x & 63, wid = threadIdx.x >> 6;
  int row = blockIdx.x * 4 + wid;
  const signed char* p = h + (size_t)row * DD;
  int s = 0;
#pragma unroll
  for (int j = 0; j < 4; ++j) {
    v4i a = *(const v4i*)(p + lane * 16 + j * 1024);
    v4i b = *(const v4i*)(w3b + lane * 16 + j * 1024);
#pragma unroll
    for (int w = 0; w < 4; ++w) {
      unsigned int xa = (unsigned int)a[w], xb = (unsigned int)b[w];
#pragma unroll
      for (int by = 0; by < 4; ++by)
        s += (int)(signed char)((xa >> (8 * by)) & 255u)
           * (int)(signed char)((xb >> (8 * by)) & 255u);
    }
  }
#pragma unroll
  for (int off = 32; off > 0; off >>= 1) s += __shfl_down(s, off);
  if (lane == 0) {
    float z = (float)s + b3[0];
    out[row] = (z >= 0.0f) ? 1.0f : -1.0f;
  }
}

extern "C" void kernel_launch(void* const* d_in, const int* in_sizes, int n_in,
                              void* d_out, int out_size, void* d_ws, size_t ws_size,
                              hipStream_t stream) {
  (void)in_sizes; (void)n_in; (void)out_size; (void)ws_size;
  const float* x  = (const float*)d_in[0];
  const float* w0 = (const float*)d_in[1];
  const float* b0 = (const float*)d_in[2];
  const float* w1 = (const float*)d_in[3];
  const float* b1 = (const float*)d_in[4];
  const float* w2 = (const float*)d_in[5];
  const float* b2 = (const float*)d_in[6];
  const float* w3 = (const float*)d_in[7];
  const float* b3 = (const float*)d_in[8];

  char* ws = (char*)d_ws;
  signed char* w0b = (signed char*)(ws + 0);            // 16 MiB
  signed char* w1b = (signed char*)(ws + 16777216);     // 16 MiB
  signed char* w2b = (signed char*)(ws + 33554432);     // 16 MiB
  signed char* w3b = (signed char*)(ws + 50331648);     // 4 KiB
  int*         R   = (int*)        (ws + 50335744);     // 16 KiB
  signed char* h1  = (signed char*)(ws + 50352128);     // 64 MiB
  signed char* h2  = (signed char*)(ws + 117460992);    // 64 MiB
  float* out = (float*)d_out;

  binarize_k<<<16384, 256, 0, stream>>>(w0, (unsigned int*)w0b, 4194304);
  binarize_k<<<16384, 256, 0, stream>>>(w1, (unsigned int*)w1b, 4194304);
  binarize_k<<<16384, 256, 0, stream>>>(w2, (unsigned int*)w2b, 4194304);
  binarize_k<<<4,     256, 0, stream>>>(w3, (unsigned int*)w3b, 1024);
  rowsum_k<<<1024, 256, 0, stream>>>(w0b, R);

  gemm0_k<<<dim3(32, 128), 512, 0, stream>>>(x, w0b, R, b0, h1);         // h1 = L0
  gemm_bin_k<<<dim3(16, 64), 512, 0, stream>>>(h1, w1b, b1, h2);         // h2 = L1
  gemm_bin_k<<<dim3(16, 64), 512, 0, stream>>>(h2, w2b, b2, h1);         // h1 = L2
  final_k<<<4096, 256, 0, stream>>>(h1, w3b, b3, out);
}